// Round 5
// baseline (539.482 us; speedup 1.0000x reference)
//
#include <hip/hip_runtime.h>
#include <hip/hip_cooperative_groups.h>

namespace cg = cooperative_groups;

#define BB 32
#define SS 2048
#define DIN 1024
#define DST 512
#define DH 256   // DST/2
#define NST 64   // MAX_STATES
#define SC 32
#define CHUNKS (SS / SC)  // 64

__device__ __forceinline__ float dot4(float4 a, float4 b) {
    return a.x * b.x + a.y * b.y + a.z * b.z + a.w * b.w;
}

// ======================= fused cooperative kernel ==========================
// 1024 blocks x 256 threads (4 blocks/CU needed -- 2x headroom vs the 8/CU
// limit that likely rejected round 4's 2048-block launch).
__global__ __launch_bounds__(256, 4) void fused_all(
        const float* __restrict__ x,
        const float* __restrict__ W1, const float* __restrict__ b1,
        const float* __restrict__ W2, const float* __restrict__ b2,
        const float* __restrict__ W3, const float* __restrict__ b3,
        const float* __restrict__ Ws1, const float* __restrict__ bs1,
        const float* __restrict__ Ws2, const float* __restrict__ bs2,
        const float* __restrict__ bank,
        float* __restrict__ out, float* __restrict__ mask_out,
        float* __restrict__ partial, float* __restrict__ pooled,
        float* __restrict__ h1, float* __restrict__ hs,
        float* __restrict__ zpart, float* __restrict__ imp) {
    cg::grid_group grid = cg::this_grid();
    int blk = blockIdx.x;
    int t = threadIdx.x;

    __shared__ float s_z[8][32];
    __shared__ float s_p[4][NST];
    __shared__ float s_imp[NST];
    __shared__ int   s_rank[NST];
    __shared__ int   s_num[BB];

    // -------- phase 0: pool partials (2 chunks/block) + bank broadcast ------
    for (int task = blk; task < BB * CHUNKS; task += 1024) {
        int b = task >> 6;
        int c = task & 63;
        const float4* xp = (const float4*)(x + ((size_t)b * SS + (size_t)c * SC) * DIN);
        float4 acc = make_float4(0.f, 0.f, 0.f, 0.f);
#pragma unroll 8
        for (int s = 0; s < SC; ++s) {
            float4 v = xp[s * (DIN / 4) + t];
            acc.x += v.x; acc.y += v.y; acc.z += v.z; acc.w += v.w;
        }
        ((float4*)(partial + (size_t)task * DIN))[t] = acc;
    }
    {
        int idx = blk * 256 + t;                 // 1024*256 = 262144 float4
        ((float4*)out)[idx] = ((const float4*)bank)[idx & 8191];
    }
    grid.sync();

    // -------- phase 1: reduce 64 partials -> pooled mean (32 blocks) --------
    if (blk < BB) {
        const float4* src = (const float4*)(partial + (size_t)blk * CHUNKS * DIN);
        float4 acc = make_float4(0.f, 0.f, 0.f, 0.f);
#pragma unroll 8
        for (int c = 0; c < CHUNKS; ++c) {
            float4 v = src[c * (DIN / 4) + t];
            acc.x += v.x; acc.y += v.y; acc.z += v.z; acc.w += v.w;
        }
        const float invS = 1.0f / (float)SS;
        acc.x *= invS; acc.y *= invS; acc.z *= invS; acc.w *= invS;
        ((float4*)(pooled + (size_t)blk * DIN))[t] = acc;
    }
    grid.sync();

    // -------- phase 2: layer1 (128 blocks) ----------------------------------
    if (blk < 64) {
        int b = t & 31;
        int j = blk * 8 + (t >> 5);
        const float4* w = (const float4*)(W1 + (size_t)j * DIN);
        const float4* p = (const float4*)(pooled + (size_t)b * DIN);
        float a0 = 0.f, a1 = 0.f;
#pragma unroll 8
        for (int k = 0; k < DIN / 4; k += 2) {
            a0 += dot4(w[k], p[k]);
            a1 += dot4(w[k + 1], p[k + 1]);
        }
        h1[(size_t)b * DST + j] = fmaxf(a0 + a1 + b1[j], 0.f);
    } else if (blk < 128) {
        int g2 = blk - 64;
        int i = t & 63;
        int j = g2 * 4 + (t >> 6);
        const float4* w = (const float4*)(Ws1 + (size_t)j * DST);
        const float4* s = (const float4*)(bank + (size_t)i * DST);
        float a0 = 0.f, a1 = 0.f;
#pragma unroll 8
        for (int k = 0; k < DST / 4; k += 2) {
            a0 += dot4(w[k], s[k]);
            a1 += dot4(w[k + 1], s[k + 1]);
        }
        hs[(size_t)i * DH + j] = fmaxf(a0 + a1 + bs1[j], 0.f);
    }
    grid.sync();

    // -------- phase 3: layer2 + z partials (32 blocks) + imp (1 block) ------
    if (blk < 32) {
        int b = t & 31;
        int jq = t >> 5;
        int j = blk * 8 + jq;
        const float4* w = (const float4*)(W2 + (size_t)j * DST);
        const float4* p = (const float4*)(h1 + (size_t)b * DST);
        float a0 = 0.f, a1 = 0.f;
#pragma unroll 8
        for (int k = 0; k < DST / 4; k += 2) {
            a0 += dot4(w[k], p[k]);
            a1 += dot4(w[k + 1], p[k + 1]);
        }
        float h2v = fmaxf(a0 + a1 + b2[j], 0.f);
        s_z[jq][b] = h2v * W3[j];
        __syncthreads();
        if (t < 32) {
            float z = 0.f;
#pragma unroll
            for (int q = 0; q < 8; ++q) z += s_z[q][t];
            zpart[blk * 32 + t] = z;
        }
    } else if (blk == 32) {
        int i = t & 63;
        int part = t >> 6;
        const float4* hv = (const float4*)(hs + (size_t)i * DH + part * 64);
        const float4* wv = (const float4*)(Ws2 + part * 64);
        float a = 0.f;
#pragma unroll
        for (int m = 0; m < 16; ++m) a += dot4(hv[m], wv[m]);
        s_p[part][i] = a;
        __syncthreads();
        if (t < NST) imp[t] = s_p[0][t] + s_p[1][t] + s_p[2][t] + s_p[3][t] + bs2[0];
    }
    grid.sync();

    // -------- phase 4: finalize (1 block) -----------------------------------
    if (blk == 0) {
        if (t < NST) s_imp[t] = imp[t];
        if (t < BB) {
            float z = 0.f;
#pragma unroll 8
            for (int g = 0; g < 32; ++g) z += zpart[g * 32 + t];
            z += b3[0];
            float cx = 1.0f / (1.0f + expf(-z));
            int ns = (int)rintf(4.0f + cx * 60.0f);   // round-half-even = jnp.round
            s_num[t] = min(max(ns, 4), 64);
        }
        __syncthreads();
        if (t < NST) {
            float mine = s_imp[t];
            int r = 0;
            for (int j = 0; j < NST; ++j) {
                float o = s_imp[j];
                if (o > mine || (o == mine && j < t)) ++r;
            }
            s_rank[t] = r;
        }
        __syncthreads();
        for (int idx = t; idx < BB * NST; idx += 256)
            mask_out[idx] = (s_rank[idx & 63] < s_num[idx >> 6]) ? 1.0f : 0.0f;
    }
}

// ======================= fallback path (round-3 kernels) ===================
__global__ void k1_pool_bcast(const float* __restrict__ x, const float* __restrict__ bank,
                              float* __restrict__ partial, float* __restrict__ out) {
    int blk = blockIdx.x;
    int t = threadIdx.x;
    if (blk < 2048) {
        int b = blk >> 6;
        int c = blk & 63;
        const float4* xp = (const float4*)(x + ((size_t)b * SS + (size_t)c * SC) * DIN);
        float4 acc = make_float4(0.f, 0.f, 0.f, 0.f);
#pragma unroll
        for (int s = 0; s < SC; ++s) {
            float4 v = xp[s * (DIN / 4) + t];
            acc.x += v.x; acc.y += v.y; acc.z += v.z; acc.w += v.w;
        }
        ((float4*)(partial + (size_t)blk * DIN))[t] = acc;
    } else {
        int idx = (blk - 2048) * 256 + t;
        ((float4*)out)[idx] = ((const float4*)bank)[idx & 8191];
    }
}

__global__ void k2_pool2(const float* __restrict__ partial, float* __restrict__ pooled) {
    int b = blockIdx.x;
    int t = threadIdx.x;
    const float4* src = (const float4*)(partial + (size_t)b * CHUNKS * DIN);
    float4 acc = make_float4(0.f, 0.f, 0.f, 0.f);
#pragma unroll 8
    for (int c = 0; c < CHUNKS; ++c) {
        float4 v = src[c * (DIN / 4) + t];
        acc.x += v.x; acc.y += v.y; acc.z += v.z; acc.w += v.w;
    }
    const float invS = 1.0f / (float)SS;
    acc.x *= invS; acc.y *= invS; acc.z *= invS; acc.w *= invS;
    ((float4*)(pooled + (size_t)b * DIN))[t] = acc;
}

__global__ void k3_layer1(const float* __restrict__ pooled,
                          const float* __restrict__ W1, const float* __restrict__ b1,
                          const float* __restrict__ Ws1, const float* __restrict__ bs1,
                          const float* __restrict__ bank,
                          float* __restrict__ h1, float* __restrict__ hs) {
    int g = blockIdx.x;
    int t = threadIdx.x;
    if (g < 64) {
        int b = t & 31;
        int j = g * 8 + (t >> 5);
        const float4* w = (const float4*)(W1 + (size_t)j * DIN);
        const float4* p = (const float4*)(pooled + (size_t)b * DIN);
        float a0 = 0.f, a1 = 0.f;
#pragma unroll 8
        for (int k = 0; k < DIN / 4; k += 2) {
            a0 += dot4(w[k], p[k]);
            a1 += dot4(w[k + 1], p[k + 1]);
        }
        h1[(size_t)b * DST + j] = fmaxf(a0 + a1 + b1[j], 0.f);
    } else {
        int g2 = g - 64;
        int i = t & 63;
        int j = g2 * 4 + (t >> 6);
        const float4* w = (const float4*)(Ws1 + (size_t)j * DST);
        const float4* s = (const float4*)(bank + (size_t)i * DST);
        float a0 = 0.f, a1 = 0.f;
#pragma unroll 8
        for (int k = 0; k < DST / 4; k += 2) {
            a0 += dot4(w[k], s[k]);
            a1 += dot4(w[k + 1], s[k + 1]);
        }
        hs[(size_t)i * DH + j] = fmaxf(a0 + a1 + bs1[j], 0.f);
    }
}

__global__ void k4_layer2(const float* __restrict__ h1,
                          const float* __restrict__ W2, const float* __restrict__ b2,
                          const float* __restrict__ hs,
                          const float* __restrict__ Ws2, const float* __restrict__ bs2,
                          const float* __restrict__ W3,
                          float* __restrict__ zpart, float* __restrict__ imp) {
    int g = blockIdx.x;
    int t = threadIdx.x;
    if (g < 32) {
        __shared__ float s_z[8][32];
        int b = t & 31;
        int jq = t >> 5;
        int j = g * 8 + jq;
        const float4* w = (const float4*)(W2 + (size_t)j * DST);
        const float4* p = (const float4*)(h1 + (size_t)b * DST);
        float a0 = 0.f, a1 = 0.f;
#pragma unroll 8
        for (int k = 0; k < DST / 4; k += 2) {
            a0 += dot4(w[k], p[k]);
            a1 += dot4(w[k + 1], p[k + 1]);
        }
        float h2v = fmaxf(a0 + a1 + b2[j], 0.f);
        s_z[jq][b] = h2v * W3[j];
        __syncthreads();
        if (t < 32) {
            float z = 0.f;
#pragma unroll
            for (int q = 0; q < 8; ++q) z += s_z[q][t];
            zpart[g * 32 + t] = z;
        }
    } else {
        __shared__ float s_p[4][NST];
        int i = t & 63;
        int part = t >> 6;
        const float4* hv = (const float4*)(hs + (size_t)i * DH + part * 64);
        const float4* wv = (const float4*)(Ws2 + part * 64);
        float a = 0.f;
#pragma unroll
        for (int m = 0; m < 16; ++m) a += dot4(hv[m], wv[m]);
        s_p[part][i] = a;
        __syncthreads();
        if (t < NST) imp[t] = s_p[0][t] + s_p[1][t] + s_p[2][t] + s_p[3][t] + bs2[0];
    }
}

__global__ void k5_final(const float* __restrict__ zpart, const float* __restrict__ b3,
                         const float* __restrict__ imp, float* __restrict__ mask_out) {
    __shared__ float s_imp[NST];
    __shared__ int s_rank[NST];
    __shared__ int s_num[BB];
    int t = threadIdx.x;
    if (t < NST) s_imp[t] = imp[t];
    if (t < BB) {
        float z = 0.f;
        for (int g = 0; g < 32; ++g) z += zpart[g * 32 + t];
        z += b3[0];
        float cx = 1.0f / (1.0f + expf(-z));
        int ns = (int)rintf(4.0f + cx * 60.0f);
        s_num[t] = min(max(ns, 4), 64);
    }
    __syncthreads();
    if (t < NST) {
        float mine = s_imp[t];
        int r = 0;
        for (int j = 0; j < NST; ++j) {
            float o = s_imp[j];
            if (o > mine || (o == mine && j < t)) ++r;
        }
        s_rank[t] = r;
    }
    __syncthreads();
    for (int idx = t; idx < BB * NST; idx += 256)
        mask_out[idx] = (s_rank[idx & 63] < s_num[idx >> 6]) ? 1.0f : 0.0f;
}

extern "C" void kernel_launch(void* const* d_in, const int* in_sizes, int n_in,
                              void* d_out, int out_size, void* d_ws, size_t ws_size,
                              hipStream_t stream) {
    const float* x    = (const float*)d_in[0];
    const float* W1   = (const float*)d_in[1];
    const float* b1   = (const float*)d_in[2];
    const float* W2   = (const float*)d_in[3];
    const float* b2   = (const float*)d_in[4];
    const float* W3   = (const float*)d_in[5];
    const float* b3   = (const float*)d_in[6];
    const float* Ws1  = (const float*)d_in[7];
    const float* bs1  = (const float*)d_in[8];
    const float* Ws2  = (const float*)d_in[9];
    const float* bs2  = (const float*)d_in[10];
    const float* bank = (const float*)d_in[11];
    // d_in[12] = temperature: unused (softmax monotonic in logits)

    float* out = (float*)d_out;
    float* mask_out = out + (size_t)BB * NST * DST;

    float* ws = (float*)d_ws;
    float* partial = ws;                                   // 8 MB
    float* pooled  = partial + (size_t)BB * CHUNKS * DIN;
    float* h1  = pooled + BB * DIN;
    float* hs  = h1 + BB * DST;
    float* zpart = hs + NST * DH;
    float* imp = zpart + 1024;

    void* args[] = {
        (void*)&x, (void*)&W1, (void*)&b1, (void*)&W2, (void*)&b2,
        (void*)&W3, (void*)&b3, (void*)&Ws1, (void*)&bs1, (void*)&Ws2,
        (void*)&bs2, (void*)&bank, (void*)&out, (void*)&mask_out,
        (void*)&partial, (void*)&pooled, (void*)&h1, (void*)&hs,
        (void*)&zpart, (void*)&imp,
    };
    hipError_t err = hipLaunchCooperativeKernel((const void*)fused_all,
                                                dim3(1024), dim3(256),
                                                args, 0, stream);
    if (err != hipSuccess) {
        // deterministic fallback: proven round-3 5-kernel path
        k1_pool_bcast<<<3072, 256, 0, stream>>>(x, bank, partial, out);
        k2_pool2<<<BB, 256, 0, stream>>>(partial, pooled);
        k3_layer1<<<128, 256, 0, stream>>>(pooled, W1, b1, Ws1, bs1, bank, h1, hs);
        k4_layer2<<<33, 256, 0, stream>>>(h1, W2, b2, hs, Ws2, bs2, W3, zpart, imp);
        k5_final<<<1, 256, 0, stream>>>(zpart, b3, imp, mask_out);
    }
}

// Round 6
// 140.639 us; speedup vs baseline: 3.8359x; 3.8359x over previous
//
#include <hip/hip_runtime.h>

#define BB 32
#define SS 2048
#define DIN 1024
#define DST 512
#define DH 256   // DST/2
#define NST 64   // MAX_STATES
#define SC 32
#define CHUNKS (SS / SC)  // 64

__device__ __forceinline__ float dot4(float4 a, float4 b) {
    return a.x * b.x + a.y * b.y + a.z * b.z + a.w * b.w;
}

__device__ __forceinline__ float wave_reduce(float d) {
    d += __shfl_xor(d, 1);
    d += __shfl_xor(d, 2);
    d += __shfl_xor(d, 4);
    d += __shfl_xor(d, 8);
    d += __shfl_xor(d, 16);
    d += __shfl_xor(d, 32);
    return d;
}

// ============ K1: pool partials + bank broadcast + fused hs->imp ============
// blocks 0..63      : importance logit for state i=blk (hs row never stored)
// blocks 64..2111   : pool partial sums (task = blk-64)
// blocks 2112..3135 : broadcast state_bank -> allocated_states
__global__ void k1_pool_imp_bcast(const float* __restrict__ x,
                                  const float* __restrict__ bank,
                                  const float* __restrict__ Ws1, const float* __restrict__ bs1,
                                  const float* __restrict__ Ws2, const float* __restrict__ bs2,
                                  float* __restrict__ partial, float* __restrict__ imp,
                                  float* __restrict__ out) {
    int blk = blockIdx.x;
    int t = threadIdx.x;
    if (blk >= 64 && blk < 64 + 2048) {
        int task = blk - 64;
        int b = task >> 6;        // batch
        int c = task & 63;        // chunk of 32 seq rows
        const float4* xp = (const float4*)(x + ((size_t)b * SS + (size_t)c * SC) * DIN);
        float4 acc = make_float4(0.f, 0.f, 0.f, 0.f);
#pragma unroll 8
        for (int s = 0; s < SC; ++s) {
            float4 v = xp[s * (DIN / 4) + t];
            acc.x += v.x; acc.y += v.y; acc.z += v.z; acc.w += v.w;
        }
        ((float4*)(partial + (size_t)task * DIN))[t] = acc;
    } else if (blk < 64) {
        // imp[i] = sum_j relu(dot(bank_i, Ws1_j) + bs1_j) * Ws2[j] + bs2
        int i = blk;
        int w = t >> 6, lane = t & 63;
        __shared__ float s_zp[4];
        const float4* brow = (const float4*)(bank + (size_t)i * DST);
        float4 p0 = brow[lane * 2];        // lane-split k: coalesced
        float4 p1 = brow[lane * 2 + 1];
        float zacc = 0.f;
        for (int jt = 0; jt < 64; ++jt) {
            int j = jt * 4 + w;            // wave w handles j % 4 == w
            const float4* wrow = (const float4*)(Ws1 + (size_t)j * DST);
            float d = dot4(wrow[lane * 2], p0) + dot4(wrow[lane * 2 + 1], p1);
            d = wave_reduce(d);
            if (lane == 0) zacc += fmaxf(d + bs1[j], 0.f) * Ws2[j];
        }
        if (lane == 0) s_zp[w] = zacc;
        __syncthreads();
        if (t == 0) imp[i] = s_zp[0] + s_zp[1] + s_zp[2] + s_zp[3] + bs2[0];
    } else {
        int idx = (blk - 2112) * 256 + t;  // 1024*256 = 262144 float4
        ((float4*)out)[idx] = ((const float4*)bank)[idx & 8191];
    }
}

// ============ K2: per-(batch, j-chunk): pool2 in-block + h1 chunk ===========
// 128 blocks: b = blk>>2, jc = blk&3; h1[b][jc*128 .. jc*128+127]
__global__ void k2_h1(const float* __restrict__ partial,
                      const float* __restrict__ W1, const float* __restrict__ b1,
                      float* __restrict__ h1) {
    int blk = blockIdx.x;
    int t = threadIdx.x;
    int b = blk >> 2, jc = blk & 3;
    __shared__ float4 s_pool[256];

    // stage A: reduce 64 partials -> pooled_b (mean)
    const float4* src = (const float4*)(partial + (size_t)b * CHUNKS * DIN);
    float4 acc = make_float4(0.f, 0.f, 0.f, 0.f);
#pragma unroll 8
    for (int c = 0; c < CHUNKS; ++c) {
        float4 v = src[c * (DIN / 4) + t];
        acc.x += v.x; acc.y += v.y; acc.z += v.z; acc.w += v.w;
    }
    const float invS = 1.0f / (float)SS;
    acc.x *= invS; acc.y *= invS; acc.z *= invS; acc.w *= invS;
    s_pool[t] = acc;
    __syncthreads();

    // stage B: wave-per-j GEMV, lane-split k (coalesced W1 reads)
    int w = t >> 6, lane = t & 63;
    float4 p[4];
#pragma unroll
    for (int m = 0; m < 4; ++m) p[m] = s_pool[lane * 4 + m];
    for (int jt = 0; jt < 32; ++jt) {
        int j = jc * 128 + jt * 4 + w;
        const float4* wrow = (const float4*)(W1 + (size_t)j * DIN);
        float d = 0.f;
#pragma unroll
        for (int m = 0; m < 4; ++m) d += dot4(wrow[lane * 4 + m], p[m]);
        d = wave_reduce(d);
        if (lane == 0) h1[(size_t)b * DST + j] = fmaxf(d + b1[j], 0.f);
    }
}

// ============ K3: per-batch: h2 -> z -> num_states; ranks; mask row =========
// 32 blocks, one per batch
__global__ void k3_final(const float* __restrict__ h1,
                         const float* __restrict__ W2, const float* __restrict__ b2,
                         const float* __restrict__ W3, const float* __restrict__ b3,
                         const float* __restrict__ imp,
                         float* __restrict__ mask_out) {
    int b = blockIdx.x;
    int t = threadIdx.x;
    int w = t >> 6, lane = t & 63;
    __shared__ float s_zp[4];
    __shared__ float s_imp[NST];
    __shared__ int s_ns;

    const float4* hrow = (const float4*)(h1 + (size_t)b * DST);
    float4 h0 = hrow[lane * 2];
    float4 h1r = hrow[lane * 2 + 1];
    float zacc = 0.f;
    for (int jt = 0; jt < 64; ++jt) {
        int j = jt * 4 + w;
        const float4* wrow = (const float4*)(W2 + (size_t)j * DST);
        float d = dot4(wrow[lane * 2], h0) + dot4(wrow[lane * 2 + 1], h1r);
        d = wave_reduce(d);
        if (lane == 0) zacc += fmaxf(d + b2[j], 0.f) * W3[j];
    }
    if (lane == 0) s_zp[w] = zacc;
    if (t < NST) s_imp[t] = imp[t];
    __syncthreads();
    if (t == 0) {
        float z = s_zp[0] + s_zp[1] + s_zp[2] + s_zp[3] + b3[0];
        float cx = 1.0f / (1.0f + expf(-z));
        int ns = (int)rintf(4.0f + cx * 60.0f);   // round-half-even = jnp.round
        s_ns = min(max(ns, 4), 64);
    }
    __syncthreads();
    if (t < NST) {
        // rank in descending importance; stable argsort tie-break: lower idx wins
        float mine = s_imp[t];
        int r = 0;
        for (int j = 0; j < NST; ++j) {
            float o = s_imp[j];
            if (o > mine || (o == mine && j < t)) ++r;
        }
        mask_out[b * NST + t] = (r < s_ns) ? 1.0f : 0.0f;
    }
}

extern "C" void kernel_launch(void* const* d_in, const int* in_sizes, int n_in,
                              void* d_out, int out_size, void* d_ws, size_t ws_size,
                              hipStream_t stream) {
    const float* x    = (const float*)d_in[0];
    const float* W1   = (const float*)d_in[1];
    const float* b1   = (const float*)d_in[2];
    const float* W2   = (const float*)d_in[3];
    const float* b2   = (const float*)d_in[4];
    const float* W3   = (const float*)d_in[5];
    const float* b3   = (const float*)d_in[6];
    const float* Ws1  = (const float*)d_in[7];
    const float* bs1  = (const float*)d_in[8];
    const float* Ws2  = (const float*)d_in[9];
    const float* bs2  = (const float*)d_in[10];
    const float* bank = (const float*)d_in[11];
    // d_in[12] = temperature: unused — softmax with positive temp is monotonic,
    // so ranks of raw logits equal ranks of importance.

    float* out = (float*)d_out;
    float* mask_out = out + (size_t)BB * NST * DST;

    float* ws = (float*)d_ws;
    float* partial = ws;                                   // 2048*1024 floats (8 MB)
    float* h1  = partial + (size_t)BB * CHUNKS * DIN;      // 16384
    float* imp = h1 + (size_t)BB * DST;                    // 64

    k1_pool_imp_bcast<<<3136, 256, 0, stream>>>(x, bank, Ws1, bs1, Ws2, bs2,
                                                partial, imp, out);
    k2_h1<<<128, 256, 0, stream>>>(partial, W1, b1, h1);
    k3_final<<<32, 256, 0, stream>>>(h1, W2, b2, W3, b3, imp, mask_out);
}